// Round 6
// baseline (937.277 us; speedup 1.0000x reference)
//
#include <hip/hip_runtime.h>

// ---------------------------------------------------------------------------
// GDN attention block, MI355X (gfx950).
//   1. cast x -> bf16
//   2. transpose weights -> bf16 B^T packs (+ Wf|Wl pack)
//   3. bf16 MFMA GEMM (128x128 tile, global_load_lds w16), bf16 outputs
//   4. fl_gemm: alpha/beta = sigmoid(x@[Wf Wl]+b) via MFMA (M=8192,N=32)
//   5. prep: causal dwconv(K=4) + head rmsnorm + low-rank mix + k-tilde norm
//   6. scan: gated delta rule. 8 blocks/bh x 2 waves; wave = 4 rows x 16
//      lanes (4 chans). Three independent reduces per step (m.k, m.q, k.q),
//      o = a*(m.q) + bd*(k.q); pure-DPP reduces; gates via readlane (no LDS).
//      DS ops: 2x b128 + 1x b32 broadcast per step per wave.
//   7. rmsnorm over D=1024 -> bf16
//   8. GEMM @ Wo -> d_out f32
// ---------------------------------------------------------------------------

typedef __attribute__((ext_vector_type(8))) short short8;
typedef __attribute__((ext_vector_type(4))) float f32x4;

#define B_ 2
#define S_ 4096
#define D_ 1024
#define H_ 16
#define R_ 48
#define M_ 8192  // B*S
#define CHUNK 32

__device__ __forceinline__ unsigned short f2bf(float f) {
  unsigned u = __float_as_uint(f);
  u += 0x7FFFu + ((u >> 16) & 1u);
  return (unsigned short)(u >> 16);
}
__device__ __forceinline__ float bf2f(unsigned short u) {
  return __uint_as_float(((unsigned)u) << 16);
}

template <int CTRL>
__device__ __forceinline__ float dppadd(float x) {
  return x + __int_as_float(__builtin_amdgcn_update_dpp(
                 0, __float_as_int(x), CTRL, 0xF, 0xF, true));
}
// sum across a 16-lane DPP row: all lanes get the sum.
__device__ __forceinline__ float redrow16(float x) {
  x = dppadd<0xB1>(x);   // quad_perm [1,0,3,2]  (xor 1)
  x = dppadd<0x4E>(x);   // quad_perm [2,3,0,1]  (xor 2)
  x = dppadd<0x128>(x);  // row_ror:8
  x = dppadd<0x124>(x);  // row_ror:4
  return x;
}

#define GLDS16(g, l) __builtin_amdgcn_global_load_lds(                        \
    (const __attribute__((address_space(1))) unsigned int*)(g),              \
    (__attribute__((address_space(3))) unsigned int*)(l), 16, 0, 0)

// --------------------------------------------------------------- cast x->bf16
__global__ __launch_bounds__(256) void cast_bf16_kernel(
    const float* __restrict__ in, unsigned short* __restrict__ out, int n4) {
  int i = blockIdx.x * 256 + threadIdx.x;
  for (; i < n4; i += gridDim.x * 256) {
    float4 v = ((const float4*)in)[i];
    ushort4 o;
    o.x = f2bf(v.x); o.y = f2bf(v.y); o.z = f2bf(v.z); o.w = f2bf(v.w);
    ((ushort4*)out)[i] = o;
  }
}

// ------------------------------------------------- W[K][N] -> Wt[N][K] (bf16)
__global__ void transpose_w_kernel(const float* __restrict__ W,
                                   unsigned short* __restrict__ Wt,
                                   int Kd, int N) {
  __shared__ float tile[32][33];
  int n0 = blockIdx.x * 32, k0 = blockIdx.y * 32;
  int tx = threadIdx.x, ty = threadIdx.y;  // 32 x 8
#pragma unroll
  for (int i = 0; i < 32; i += 8)
    tile[ty + i][tx] = W[(size_t)(k0 + ty + i) * N + n0 + tx];
  __syncthreads();
#pragma unroll
  for (int i = 0; i < 32; i += 8)
    Wt[(size_t)(n0 + ty + i) * Kd + k0 + tx] = f2bf(tile[tx][ty + i]);
}

// -------------------------------------- pack [Wf|Wl] -> wfl[32][1024] bf16
__global__ __launch_bounds__(256) void pack_wfl_kernel(
    const float* __restrict__ Wf, const float* __restrict__ Wl,
    unsigned short* __restrict__ wfl) {
  int o = blockIdx.x * 256 + threadIdx.x;  // 32768 total
  int j = o >> 10, k = o & 1023;
  float v = (j < 16) ? Wf[k * 16 + j] : Wl[k * 16 + (j - 16)];
  wfl[o] = f2bf(v);
}

// ------------------------------------------------------------- bf16 MFMA GEMM
template <bool BF16OUT>
__global__ __launch_bounds__(256) void gemm_bt_kernel(
    const unsigned short* __restrict__ A, const unsigned short* __restrict__ Bt,
    void* __restrict__ Cv, int M, int N, int Kd) {
  __shared__ alignas(16) unsigned short lds[2 * 128 * 64];  // 32 KiB
  unsigned short* ldsA = lds;
  unsigned short* ldsB = lds + 128 * 64;
  int tid = threadIdx.x;
  int wave = tid >> 6, lane = tid & 63;
  int nBlocks = N >> 7;
  int bm = blockIdx.x / nBlocks, bn = blockIdx.x % nBlocks;
  int m0 = bm << 7, n0 = bn << 7;
  int wm = (wave >> 1) << 6, wn = (wave & 1) << 6;

  f32x4 acc[4][4] = {};

  int rowInChunk = lane >> 3;
  int kOff = (lane & 7) * 8;

  const unsigned short* Abase = A + (size_t)m0 * Kd;
  const unsigned short* Bbase = Bt + (size_t)n0 * Kd;

  for (int k0 = 0; k0 < Kd; k0 += 64) {
    __syncthreads();
#pragma unroll
    for (int r = 0; r < 4; r++) {
      int c = wave * 4 + r;
      int row = c * 8 + rowInChunk;
      GLDS16(Abase + (size_t)row * Kd + k0 + kOff, ldsA + c * 512);
    }
#pragma unroll
    for (int r = 0; r < 4; r++) {
      int c = wave * 4 + r;
      int row = c * 8 + rowInChunk;
      GLDS16(Bbase + (size_t)row * Kd + k0 + kOff, ldsB + c * 512);
    }
    asm volatile("s_waitcnt vmcnt(0)" ::: "memory");
    __syncthreads();
#pragma unroll
    for (int kk = 0; kk < 2; kk++) {
      short8 af[4], bfr[4];
      int kb = kk * 32 + (lane >> 4) * 8;
#pragma unroll
      for (int i = 0; i < 4; i++) {
        int ar = wm + i * 16 + (lane & 15);
        af[i] = *(const short8*)(ldsA + ar * 64 + kb);
        int br = wn + i * 16 + (lane & 15);
        bfr[i] = *(const short8*)(ldsB + br * 64 + kb);
      }
#pragma unroll
      for (int i = 0; i < 4; i++)
#pragma unroll
        for (int j = 0; j < 4; j++)
          acc[i][j] = __builtin_amdgcn_mfma_f32_16x16x32_bf16(
              af[i], bfr[j], acc[i][j], 0, 0, 0);
    }
  }
  int cr = (lane >> 4) * 4;
  int cc = lane & 15;
#pragma unroll
  for (int i = 0; i < 4; i++)
#pragma unroll
    for (int j = 0; j < 4; j++)
#pragma unroll
      for (int rg = 0; rg < 4; rg++) {
        int row = m0 + wm + i * 16 + cr + rg;
        int col = n0 + wn + j * 16 + cc;
        if (BF16OUT)
          ((unsigned short*)Cv)[(size_t)row * N + col] = f2bf(acc[i][j][rg]);
        else
          ((float*)Cv)[(size_t)row * N + col] = acc[i][j][rg];
      }
}

// ---------------------------- alpha/beta via MFMA: [8192x1024]@[32x1024]^T
__global__ __launch_bounds__(256) void fl_gemm_kernel(
    const unsigned short* __restrict__ xb, const unsigned short* __restrict__ wfl,
    const float* __restrict__ bfv, const float* __restrict__ blv,
    float* __restrict__ alpha, float* __restrict__ beta) {
  __shared__ alignas(16) unsigned short ldsA[128 * 64];
  __shared__ alignas(16) unsigned short ldsB[32 * 64];
  int tid = threadIdx.x, wave = tid >> 6, lane = tid & 63;
  int m0 = blockIdx.x << 7;
  f32x4 acc[2][2] = {};
  int rowInChunk = lane >> 3, kOff = (lane & 7) * 8;
  const unsigned short* Abase = xb + (size_t)m0 * 1024;

  for (int k0 = 0; k0 < 1024; k0 += 64) {
    __syncthreads();
#pragma unroll
    for (int r = 0; r < 4; r++) {
      int ch = wave * 4 + r;
      int row = ch * 8 + rowInChunk;
      GLDS16(Abase + (size_t)row * 1024 + k0 + kOff, ldsA + ch * 512);
    }
    {
      int row = wave * 8 + rowInChunk;
      GLDS16(wfl + (size_t)row * 1024 + k0 + kOff, ldsB + wave * 512);
    }
    asm volatile("s_waitcnt vmcnt(0)" ::: "memory");
    __syncthreads();
#pragma unroll
    for (int kk = 0; kk < 2; kk++) {
      int kb2 = kk * 32 + (lane >> 4) * 8;
      short8 af[2], bfr[2];
#pragma unroll
      for (int i = 0; i < 2; i++)
        af[i] = *(const short8*)(ldsA + (wave * 32 + i * 16 + (lane & 15)) * 64 + kb2);
#pragma unroll
      for (int j = 0; j < 2; j++)
        bfr[j] = *(const short8*)(ldsB + (j * 16 + (lane & 15)) * 64 + kb2);
#pragma unroll
      for (int i = 0; i < 2; i++)
#pragma unroll
        for (int j = 0; j < 2; j++)
          acc[i][j] = __builtin_amdgcn_mfma_f32_16x16x32_bf16(
              af[i], bfr[j], acc[i][j], 0, 0, 0);
    }
  }
  int cr = (lane >> 4) * 4, cc = lane & 15;
#pragma unroll
  for (int i = 0; i < 2; i++)
#pragma unroll
    for (int j = 0; j < 2; j++)
#pragma unroll
      for (int rg = 0; rg < 4; rg++) {
        int row = m0 + wave * 32 + i * 16 + cr + rg;
        int col = j * 16 + cc;
        float z = acc[i][j][rg] + ((col < 16) ? bfv[col] : blv[col - 16]);
        float s = 1.f / (1.f + __expf(-z));
        int bb = row >> 12, tt = row & 4095, hh = col & 15;
        float* dst = (col < 16) ? alpha : beta;
        dst[((size_t)(bb * 16 + hh)) * 4096 + tt] = s;
      }
}

// ------------------------ conv + rmsnorm + low-rank mix + k-tilde normalize
__global__ __launch_bounds__(256) void prep_kernel(
    const unsigned short* __restrict__ xqkv, const unsigned short* __restrict__ rqk,
    const float* __restrict__ cq, const float* __restrict__ ck,
    const float* __restrict__ cv, const float* __restrict__ gs,
    const float* __restrict__ qnw, const float* __restrict__ knw,
    unsigned short* __restrict__ qt, unsigned short* __restrict__ kt,
    unsigned short* __restrict__ vc) {
  int m = blockIdx.x;
  int b = m >> 12, t = m & 4095;
  int tid = threadIdx.x;
  int c4 = tid << 2;
  int h = c4 >> 6;
  int j4 = c4 & 63;

  float wq[4][4], wk[4][4], wv[4][4];
#pragma unroll
  for (int u = 0; u < 4; u++) {
    *(float4*)wq[u] = *(const float4*)(cq + (c4 + u) * 4);
    *(float4*)wk[u] = *(const float4*)(ck + (c4 + u) * 4);
    *(float4*)wv[u] = *(const float4*)(cv + (c4 + u) * 4);
  }
  float qv[4] = {0, 0, 0, 0}, kv[4] = {0, 0, 0, 0}, vv[4] = {0, 0, 0, 0};
#pragma unroll
  for (int j = 0; j < 4; j++) {
    int tt = t + j - 3;
    if (tt < 0) continue;
    const unsigned short* xr = xqkv + ((size_t)((b << 12) + tt)) * 3072;
    ushort4 uq = *(const ushort4*)(xr + c4);
    ushort4 uk = *(const ushort4*)(xr + 1024 + c4);
    ushort4 uv = *(const ushort4*)(xr + 2048 + c4);
    float xq[4] = {bf2f(uq.x), bf2f(uq.y), bf2f(uq.z), bf2f(uq.w)};
    float xk[4] = {bf2f(uk.x), bf2f(uk.y), bf2f(uk.z), bf2f(uk.w)};
    float xv[4] = {bf2f(uv.x), bf2f(uv.y), bf2f(uv.z), bf2f(uv.w)};
#pragma unroll
    for (int u = 0; u < 4; u++) {
      qv[u] = fmaf(wq[u][j], xq[u], qv[u]);
      kv[u] = fmaf(wk[u][j], xk[u], kv[u]);
      vv[u] = fmaf(wv[u][j], xv[u], vv[u]);
    }
  }
  float ssq = qv[0] * qv[0] + qv[1] * qv[1] + qv[2] * qv[2] + qv[3] * qv[3];
  ssq += __shfl_xor(ssq, 1); ssq += __shfl_xor(ssq, 2);
  ssq += __shfl_xor(ssq, 4); ssq += __shfl_xor(ssq, 8);
  float qsc = rsqrtf(ssq * (1.f / 64.f) + 1e-6f);
  float ssk = kv[0] * kv[0] + kv[1] * kv[1] + kv[2] * kv[2] + kv[3] * kv[3];
  ssk += __shfl_xor(ssk, 1); ssk += __shfl_xor(ssk, 2);
  ssk += __shfl_xor(ssk, 4); ssk += __shfl_xor(ssk, 8);
  float ksc = rsqrtf(ssk * (1.f / 64.f) + 1e-6f);

  float lam = fabsf(gs[h]);
  float rq[4] = {0, 0, 0, 0}, rk[4] = {0, 0, 0, 0};
  if (j4 < R_) {
    const unsigned short* rr = rqk + (size_t)m * 1536;
    ushort4 uq = *(const ushort4*)(rr + h * R_ + j4);
    ushort4 uk = *(const ushort4*)(rr + 768 + h * R_ + j4);
    rq[0] = bf2f(uq.x); rq[1] = bf2f(uq.y); rq[2] = bf2f(uq.z); rq[3] = bf2f(uq.w);
    rk[0] = bf2f(uk.x); rk[1] = bf2f(uk.y); rk[2] = bf2f(uk.z); rk[3] = bf2f(uk.w);
  }
  float qtv[4], ksum[4];
#pragma unroll
  for (int u = 0; u < 4; u++) {
    float qn = qv[u] * qsc * qnw[j4 + u];
    float kn = kv[u] * ksc * knw[j4 + u];
    qtv[u] = fmaf(lam, rq[u], qn);
    ksum[u] = fmaf(lam, rk[u], kn);
  }
  float ss2 = ksum[0] * ksum[0] + ksum[1] * ksum[1] + ksum[2] * ksum[2] +
              ksum[3] * ksum[3];
  ss2 += __shfl_xor(ss2, 1); ss2 += __shfl_xor(ss2, 2);
  ss2 += __shfl_xor(ss2, 4); ss2 += __shfl_xor(ss2, 8);
  float inv = 1.f / fmaxf(sqrtf(ss2), 1e-12f);

  size_t ob = ((size_t)((b * 16 + h) * 4096 + t)) * 64 + j4;
  ushort4 oq, ok, ov;
  oq.x = f2bf(qtv[0]); oq.y = f2bf(qtv[1]); oq.z = f2bf(qtv[2]); oq.w = f2bf(qtv[3]);
  ok.x = f2bf(ksum[0] * inv); ok.y = f2bf(ksum[1] * inv);
  ok.z = f2bf(ksum[2] * inv); ok.w = f2bf(ksum[3] * inv);
  ov.x = f2bf(vv[0]); ov.y = f2bf(vv[1]); ov.z = f2bf(vv[2]); ov.w = f2bf(vv[3]);
  *(ushort4*)(qt + ob) = oq;
  *(ushort4*)(kt + ob) = ok;
  *(ushort4*)(vc + ob) = ov;
}

// -------------------------------------------------------- gated delta scan
// 256 blocks (8 per bh, same-XCD), 2 waves/block, wave = 4 rows x 16 lanes.
// Per step: 2x ds_read_b128 + 1x ds_read_b32 (broadcast); gates via readlane;
// three independent DPP reduces; o = a*mq + bd*kq.
__global__ __launch_bounds__(128) void scan_kernel(
    const unsigned short* __restrict__ qt, const unsigned short* __restrict__ kt,
    const unsigned short* __restrict__ vc, const float* __restrict__ al,
    const float* __restrict__ be, float* __restrict__ attn) {
  __shared__ alignas(16) float sk[2][CHUNK][64];
  __shared__ alignas(16) float sq[2][CHUNK][64];
  __shared__ alignas(16) float sv[2][CHUNK][8];

  int i = blockIdx.x;
  int bh = i & 31;   // i%8 == bh%8 -> all 8 blocks of a bh on one XCD
  int grp = i >> 5;  // 0..7 -> rows grp*8..+7
  int b = bh >> 4, h = bh & 15;
  int tid = threadIdx.x;
  int w = tid >> 6, l = tid & 63;
  int rw = l >> 4;        // row in wave (0..3)
  int li = l & 15;        // lane in DPP row
  int vr = w * 4 + rw;    // row in block (0..7)
  int r = grp * 8 + vr;   // global row
  int c = li * 4;

  const unsigned short* kb = kt + (size_t)bh * S_ * 64;
  const unsigned short* qb = qt + (size_t)bh * S_ * 64;
  const unsigned short* vb = vc + (size_t)bh * S_ * 64 + grp * 8;
  const float* ap = al + (size_t)bh * S_;
  const float* bp = be + (size_t)bh * S_;
  float* op = attn + (size_t)(b * S_) * 1024 + h * 64 + r;

  float mem[4] = {0.f, 0.f, 0.f, 0.f};

  // prefetch chunk 0 into regs: 16 bf16 of k and q per thread, 2 v, 1 gate.
  short8 rk0 = *(const short8*)(kb + tid * 16);
  short8 rk1 = *(const short8*)(kb + tid * 16 + 8);
  short8 rq0 = *(const short8*)(qb + tid * 16);
  short8 rq1 = *(const short8*)(qb + tid * 16 + 8);
  ushort2 rv = *(const ushort2*)(vb + (size_t)(tid >> 2) * 64 + (tid & 3) * 2);
  float rab = (l < 32) ? ap[l] : bp[l - 32];  // per-wave copy

  const int nc = S_ / CHUNK;
  for (int cch = 0; cch < nc; ++cch) {
    int p = cch & 1;
    unsigned rab_c = __float_as_uint(rab);  // preserve current-chunk gates
    __syncthreads();
    {  // regs -> LDS (bf16 -> f32). thread covers sk[p][tid>>2][(tid&3)*16..+16)
      int t = tid >> 2, ch = (tid & 3) * 16;
      float* dk = &sk[p][t][ch];
      float* dq = &sq[p][t][ch];
      f32x4 f;
#pragma unroll
      for (int j = 0; j < 4; j++) f[j] = bf2f((unsigned short)rk0[j]);
      *(f32x4*)dk = f;
#pragma unroll
      for (int j = 0; j < 4; j++) f[j] = bf2f((unsigned short)rk0[4 + j]);
      *(f32x4*)(dk + 4) = f;
#pragma unroll
      for (int j = 0; j < 4; j++) f[j] = bf2f((unsigned short)rk1[j]);
      *(f32x4*)(dk + 8) = f;
#pragma unroll
      for (int j = 0; j < 4; j++) f[j] = bf2f((unsigned short)rk1[4 + j]);
      *(f32x4*)(dk + 12) = f;
#pragma unroll
      for (int j = 0; j < 4; j++) f[j] = bf2f((unsigned short)rq0[j]);
      *(f32x4*)dq = f;
#pragma unroll
      for (int j = 0; j < 4; j++) f[j] = bf2f((unsigned short)rq0[4 + j]);
      *(f32x4*)(dq + 4) = f;
#pragma unroll
      for (int j = 0; j < 4; j++) f[j] = bf2f((unsigned short)rq1[j]);
      *(f32x4*)(dq + 8) = f;
#pragma unroll
      for (int j = 0; j < 4; j++) f[j] = bf2f((unsigned short)rq1[4 + j]);
      *(f32x4*)(dq + 12) = f;
      sv[p][tid >> 2][(tid & 3) * 2] = bf2f(rv.x);
      sv[p][tid >> 2][(tid & 3) * 2 + 1] = bf2f(rv.y);
    }
    if (cch + 1 < nc) {  // issue next-chunk loads; in flight during compute
      size_t cb = (size_t)(cch + 1) * (CHUNK * 64);
      rk0 = *(const short8*)(kb + cb + tid * 16);
      rk1 = *(const short8*)(kb + cb + tid * 16 + 8);
      rq0 = *(const short8*)(qb + cb + tid * 16);
      rq1 = *(const short8*)(qb + cb + tid * 16 + 8);
      rv = *(const ushort2*)(vb + cb + (size_t)(tid >> 2) * 64 + (tid & 3) * 2);
      int ct = (cch + 1) * CHUNK;
      rab = (l < 32) ? ap[ct + l] : bp[ct + l - 32];
    }
    __syncthreads();
    int tg0 = cch * CHUNK;
#pragma unroll 4
    for (int t = 0; t < CHUNK; t++) {
      f32x4 kf = *(const f32x4*)&sk[p][t][c];
      f32x4 qf = *(const f32x4*)&sq[p][t][c];
      float v = sv[p][t][vr];
      float a = __uint_as_float(__builtin_amdgcn_readlane(rab_c, t));
      float bg = __uint_as_float(__builtin_amdgcn_readlane(rab_c, t + 32));

      float mk_p = fmaf(mem[1], kf[1], mem[0] * kf[0]) +
                   fmaf(mem[3], kf[3], mem[2] * kf[2]);
      float mq_p = fmaf(mem[1], qf[1], mem[0] * qf[0]) +
                   fmaf(mem[3], qf[3], mem[2] * qf[2]);
      float kq_p = fmaf(kf[1], qf[1], kf[0] * qf[0]) +
                   fmaf(kf[3], qf[3], kf[2] * qf[2]);
      float mk = redrow16(mk_p);
      float mq = redrow16(mq_p);
      float kq = redrow16(kq_p);

      float bd = bg * (v - mk);
      float oo = fmaf(bd, kq, a * mq);
#pragma unroll
      for (int u = 0; u < 4; u++) mem[u] = fmaf(bd, kf[u], a * mem[u]);
      if (li == 0) op[(size_t)(tg0 + t) * 1024] = oo;
    }
  }
}

// ------------------------------------------------ output rmsnorm -> bf16 rows
__global__ __launch_bounds__(256) void rmsnorm_out_kernel(
    const float* __restrict__ attn, const float* __restrict__ onw,
    unsigned short* __restrict__ normed) {
  int m = blockIdx.x, tid = threadIdx.x;
  const float* row = attn + (size_t)m * 1024;
  float xv[4];
  *(float4*)xv = *(const float4*)(row + tid * 4);
  float ss = xv[0] * xv[0] + xv[1] * xv[1] + xv[2] * xv[2] + xv[3] * xv[3];
#pragma unroll
  for (int o = 1; o < 64; o <<= 1) ss += __shfl_xor(ss, o);
  __shared__ float wss[4];
  if ((tid & 63) == 0) wss[tid >> 6] = ss;
  __syncthreads();
  float tot = wss[0] + wss[1] + wss[2] + wss[3];
  float sc = rsqrtf(tot * (1.f / 1024.f) + 1e-6f);
  float wv[4];
  *(float4*)wv = *(const float4*)(onw + tid * 4);
  ushort4 o4;
  o4.x = f2bf(xv[0] * sc * wv[0]);
  o4.y = f2bf(xv[1] * sc * wv[1]);
  o4.z = f2bf(xv[2] * sc * wv[2]);
  o4.w = f2bf(xv[3] * sc * wv[3]);
  *(ushort4*)(normed + (size_t)m * 1024 + tid * 4) = o4;
}

// ---------------------------------------------------------------------------
extern "C" void kernel_launch(void* const* d_in, const int* in_sizes, int n_in,
                              void* d_out, int out_size, void* d_ws,
                              size_t ws_size, hipStream_t stream) {
  const float* x = (const float*)d_in[0];
  const float* Wq = (const float*)d_in[1];
  const float* Wk = (const float*)d_in[2];
  const float* Wv = (const float*)d_in[3];
  const float* Wo = (const float*)d_in[4];
  const float* conv_q = (const float*)d_in[5];
  const float* conv_k = (const float*)d_in[6];
  const float* conv_v = (const float*)d_in[7];
  const float* Wf = (const float*)d_in[8];
  const float* bfv = (const float*)d_in[9];
  const float* Wl = (const float*)d_in[10];
  const float* blv = (const float*)d_in[11];
  const float* gs = (const float*)d_in[14];
  const float* qn_w = (const float*)d_in[15];
  const float* kn_w = (const float*)d_in[16];
  const float* on_w = (const float*)d_in[17];

  char* ws = (char*)d_ws;
  size_t used = 0;
  auto alloc = [&](size_t bytes) -> void* {
    void* p = (void*)(ws + used);
    used += (bytes + 255) & ~(size_t)255;
    return p;
  };
  unsigned short* xb = (unsigned short*)alloc((size_t)M_ * D_ * 2);
  unsigned short* wqkv_t = (unsigned short*)alloc((size_t)3072 * 1024 * 2);
  unsigned short* wr_t = (unsigned short*)alloc((size_t)1536 * 1024 * 2);
  unsigned short* wo_t = (unsigned short*)alloc((size_t)1024 * 1024 * 2);
  unsigned short* wfl = (unsigned short*)alloc((size_t)32 * 1024 * 2);
  unsigned short* xqkv = (unsigned short*)alloc((size_t)M_ * 3072 * 2);
  unsigned short* rqk = (unsigned short*)alloc((size_t)M_ * 1536 * 2);
  unsigned short* qt = (unsigned short*)alloc((size_t)M_ * 1024 * 2);
  unsigned short* kt = (unsigned short*)alloc((size_t)M_ * 1024 * 2);
  unsigned short* vc = (unsigned short*)alloc((size_t)M_ * 1024 * 2);
  float* alpha = (float*)alloc((size_t)B_ * H_ * S_ * 4);
  float* beta = (float*)alloc((size_t)B_ * H_ * S_ * 4);
  float* attn = (float*)xqkv;    // alias (xqkv dead after prep)
  unsigned short* normed = rqk;  // alias (rqk dead after prep)

  if (used > ws_size) return;

  cast_bf16_kernel<<<2048, 256, 0, stream>>>(x, xb, M_ * D_ / 4);

  dim3 tb(32, 8);
  transpose_w_kernel<<<dim3(32, 32), tb, 0, stream>>>(Wq, wqkv_t, 1024, 1024);
  transpose_w_kernel<<<dim3(32, 32), tb, 0, stream>>>(
      Wk, wqkv_t + (size_t)1024 * 1024, 1024, 1024);
  transpose_w_kernel<<<dim3(32, 32), tb, 0, stream>>>(
      Wv, wqkv_t + (size_t)2048 * 1024, 1024, 1024);
  transpose_w_kernel<<<dim3(24, 32), tb, 0, stream>>>(
      (const float*)d_in[12], wr_t, 1024, 768);
  transpose_w_kernel<<<dim3(24, 32), tb, 0, stream>>>(
      (const float*)d_in[13], wr_t + (size_t)768 * 1024, 1024, 768);
  transpose_w_kernel<<<dim3(32, 32), tb, 0, stream>>>(Wo, wo_t, 1024, 1024);
  pack_wfl_kernel<<<128, 256, 0, stream>>>(Wf, Wl, wfl);

  gemm_bt_kernel<true><<<64 * 24, 256, 0, stream>>>(xb, wqkv_t, xqkv, M_, 3072, 1024);
  gemm_bt_kernel<true><<<64 * 12, 256, 0, stream>>>(xb, wr_t, rqk, M_, 1536, 1024);

  fl_gemm_kernel<<<64, 256, 0, stream>>>(xb, wfl, bfv, blv, alpha, beta);

  prep_kernel<<<M_, 256, 0, stream>>>(xqkv, rqk, conv_q, conv_k, conv_v, gs,
                                      qn_w, kn_w, qt, kt, vc);

  scan_kernel<<<256, 128, 0, stream>>>(qt, kt, vc, alpha, beta, attn);

  rmsnorm_out_kernel<<<M_, 256, 0, stream>>>(attn, on_w, normed);

  gemm_bt_kernel<false><<<64 * 8, 256, 0, stream>>>(normed, wo_t, (float*)d_out,
                                                    M_, 1024, 1024);
}

// Round 7
// 902.909 us; speedup vs baseline: 1.0381x; 1.0381x over previous
//
#include <hip/hip_runtime.h>

// ---------------------------------------------------------------------------
// GDN attention block, MI355X (gfx950).
//   1. cast x -> bf16
//   2. transpose weights -> bf16 B^T packs (+ Wf|Wl pack)
//   3. bf16 MFMA GEMM (128x128 tile, global_load_lds w16), bf16 outputs
//   4. fl_gemm: alpha/beta = sigmoid(x@[Wf Wl]+b) via MFMA (M=8192,N=32)
//   5. prep: causal dwconv(K=4) + head rmsnorm + low-rank mix + k-tilde norm
//   6. scan: gated delta rule. 8 blocks/bh x 2 waves; wave = 4 rows x 16
//      lanes (4 chans). Per 8-step group: batched LDS->reg loads (amortize
//      LDS latency), then reg-only compute. Pure-DPP 16-lane reduces; gates
//      via readlane. LDS rows padded to 65 f32 (2-way banks max).
//   7. rmsnorm over D=1024 -> bf16
//   8. GEMM @ Wo -> d_out f32
// ---------------------------------------------------------------------------

typedef __attribute__((ext_vector_type(8))) short short8;
typedef __attribute__((ext_vector_type(4))) float f32x4;

#define B_ 2
#define S_ 4096
#define D_ 1024
#define H_ 16
#define R_ 48
#define M_ 8192  // B*S
#define CHUNK 32

__device__ __forceinline__ unsigned short f2bf(float f) {
  unsigned u = __float_as_uint(f);
  u += 0x7FFFu + ((u >> 16) & 1u);
  return (unsigned short)(u >> 16);
}
__device__ __forceinline__ float bf2f(unsigned short u) {
  return __uint_as_float(((unsigned)u) << 16);
}

template <int CTRL>
__device__ __forceinline__ float dppadd(float x) {
  return x + __int_as_float(__builtin_amdgcn_update_dpp(
                 0, __float_as_int(x), CTRL, 0xF, 0xF, true));
}
// sum across a 16-lane DPP row: all lanes get the sum.
__device__ __forceinline__ float redrow16(float x) {
  x = dppadd<0xB1>(x);   // quad_perm [1,0,3,2]  (xor 1)
  x = dppadd<0x4E>(x);   // quad_perm [2,3,0,1]  (xor 2)
  x = dppadd<0x128>(x);  // row_ror:8
  x = dppadd<0x124>(x);  // row_ror:4
  return x;
}

#define GLDS16(g, l) __builtin_amdgcn_global_load_lds(                        \
    (const __attribute__((address_space(1))) unsigned int*)(g),              \
    (__attribute__((address_space(3))) unsigned int*)(l), 16, 0, 0)

// --------------------------------------------------------------- cast x->bf16
__global__ __launch_bounds__(256) void cast_bf16_kernel(
    const float* __restrict__ in, unsigned short* __restrict__ out, int n4) {
  int i = blockIdx.x * 256 + threadIdx.x;
  for (; i < n4; i += gridDim.x * 256) {
    float4 v = ((const float4*)in)[i];
    ushort4 o;
    o.x = f2bf(v.x); o.y = f2bf(v.y); o.z = f2bf(v.z); o.w = f2bf(v.w);
    ((ushort4*)out)[i] = o;
  }
}

// ------------------------------------------------- W[K][N] -> Wt[N][K] (bf16)
__global__ void transpose_w_kernel(const float* __restrict__ W,
                                   unsigned short* __restrict__ Wt,
                                   int Kd, int N) {
  __shared__ float tile[32][33];
  int n0 = blockIdx.x * 32, k0 = blockIdx.y * 32;
  int tx = threadIdx.x, ty = threadIdx.y;  // 32 x 8
#pragma unroll
  for (int i = 0; i < 32; i += 8)
    tile[ty + i][tx] = W[(size_t)(k0 + ty + i) * N + n0 + tx];
  __syncthreads();
#pragma unroll
  for (int i = 0; i < 32; i += 8)
    Wt[(size_t)(n0 + ty + i) * Kd + k0 + tx] = f2bf(tile[tx][ty + i]);
}

// -------------------------------------- pack [Wf|Wl] -> wfl[32][1024] bf16
__global__ __launch_bounds__(256) void pack_wfl_kernel(
    const float* __restrict__ Wf, const float* __restrict__ Wl,
    unsigned short* __restrict__ wfl) {
  int o = blockIdx.x * 256 + threadIdx.x;  // 32768 total
  int j = o >> 10, k = o & 1023;
  float v = (j < 16) ? Wf[k * 16 + j] : Wl[k * 16 + (j - 16)];
  wfl[o] = f2bf(v);
}

// ------------------------------------------------------------- bf16 MFMA GEMM
template <bool BF16OUT>
__global__ __launch_bounds__(256) void gemm_bt_kernel(
    const unsigned short* __restrict__ A, const unsigned short* __restrict__ Bt,
    void* __restrict__ Cv, int M, int N, int Kd) {
  __shared__ alignas(16) unsigned short lds[2 * 128 * 64];  // 32 KiB
  unsigned short* ldsA = lds;
  unsigned short* ldsB = lds + 128 * 64;
  int tid = threadIdx.x;
  int wave = tid >> 6, lane = tid & 63;
  int nBlocks = N >> 7;
  int bm = blockIdx.x / nBlocks, bn = blockIdx.x % nBlocks;
  int m0 = bm << 7, n0 = bn << 7;
  int wm = (wave >> 1) << 6, wn = (wave & 1) << 6;

  f32x4 acc[4][4] = {};

  int rowInChunk = lane >> 3;
  int kOff = (lane & 7) * 8;

  const unsigned short* Abase = A + (size_t)m0 * Kd;
  const unsigned short* Bbase = Bt + (size_t)n0 * Kd;

  for (int k0 = 0; k0 < Kd; k0 += 64) {
    __syncthreads();
#pragma unroll
    for (int r = 0; r < 4; r++) {
      int c = wave * 4 + r;
      int row = c * 8 + rowInChunk;
      GLDS16(Abase + (size_t)row * Kd + k0 + kOff, ldsA + c * 512);
    }
#pragma unroll
    for (int r = 0; r < 4; r++) {
      int c = wave * 4 + r;
      int row = c * 8 + rowInChunk;
      GLDS16(Bbase + (size_t)row * Kd + k0 + kOff, ldsB + c * 512);
    }
    asm volatile("s_waitcnt vmcnt(0)" ::: "memory");
    __syncthreads();
#pragma unroll
    for (int kk = 0; kk < 2; kk++) {
      short8 af[4], bfr[4];
      int kb = kk * 32 + (lane >> 4) * 8;
#pragma unroll
      for (int i = 0; i < 4; i++) {
        int ar = wm + i * 16 + (lane & 15);
        af[i] = *(const short8*)(ldsA + ar * 64 + kb);
        int br = wn + i * 16 + (lane & 15);
        bfr[i] = *(const short8*)(ldsB + br * 64 + kb);
      }
#pragma unroll
      for (int i = 0; i < 4; i++)
#pragma unroll
        for (int j = 0; j < 4; j++)
          acc[i][j] = __builtin_amdgcn_mfma_f32_16x16x32_bf16(
              af[i], bfr[j], acc[i][j], 0, 0, 0);
    }
  }
  int cr = (lane >> 4) * 4;
  int cc = lane & 15;
#pragma unroll
  for (int i = 0; i < 4; i++)
#pragma unroll
    for (int j = 0; j < 4; j++)
#pragma unroll
      for (int rg = 0; rg < 4; rg++) {
        int row = m0 + wm + i * 16 + cr + rg;
        int col = n0 + wn + j * 16 + cc;
        if (BF16OUT)
          ((unsigned short*)Cv)[(size_t)row * N + col] = f2bf(acc[i][j][rg]);
        else
          ((float*)Cv)[(size_t)row * N + col] = acc[i][j][rg];
      }
}

// ---------------------------- alpha/beta via MFMA: [8192x1024]@[32x1024]^T
__global__ __launch_bounds__(256) void fl_gemm_kernel(
    const unsigned short* __restrict__ xb, const unsigned short* __restrict__ wfl,
    const float* __restrict__ bfv, const float* __restrict__ blv,
    float* __restrict__ alpha, float* __restrict__ beta) {
  __shared__ alignas(16) unsigned short ldsA[128 * 64];
  __shared__ alignas(16) unsigned short ldsB[32 * 64];
  int tid = threadIdx.x, wave = tid >> 6, lane = tid & 63;
  int m0 = blockIdx.x << 7;
  f32x4 acc[2][2] = {};
  int rowInChunk = lane >> 3, kOff = (lane & 7) * 8;
  const unsigned short* Abase = xb + (size_t)m0 * 1024;

  for (int k0 = 0; k0 < 1024; k0 += 64) {
    __syncthreads();
#pragma unroll
    for (int r = 0; r < 4; r++) {
      int ch = wave * 4 + r;
      int row = ch * 8 + rowInChunk;
      GLDS16(Abase + (size_t)row * 1024 + k0 + kOff, ldsA + ch * 512);
    }
    {
      int row = wave * 8 + rowInChunk;
      GLDS16(wfl + (size_t)row * 1024 + k0 + kOff, ldsB + wave * 512);
    }
    asm volatile("s_waitcnt vmcnt(0)" ::: "memory");
    __syncthreads();
#pragma unroll
    for (int kk = 0; kk < 2; kk++) {
      int kb2 = kk * 32 + (lane >> 4) * 8;
      short8 af[2], bfr[2];
#pragma unroll
      for (int i = 0; i < 2; i++)
        af[i] = *(const short8*)(ldsA + (wave * 32 + i * 16 + (lane & 15)) * 64 + kb2);
#pragma unroll
      for (int j = 0; j < 2; j++)
        bfr[j] = *(const short8*)(ldsB + (j * 16 + (lane & 15)) * 64 + kb2);
#pragma unroll
      for (int i = 0; i < 2; i++)
#pragma unroll
        for (int j = 0; j < 2; j++)
          acc[i][j] = __builtin_amdgcn_mfma_f32_16x16x32_bf16(
              af[i], bfr[j], acc[i][j], 0, 0, 0);
    }
  }
  int cr = (lane >> 4) * 4, cc = lane & 15;
#pragma unroll
  for (int i = 0; i < 2; i++)
#pragma unroll
    for (int j = 0; j < 2; j++)
#pragma unroll
      for (int rg = 0; rg < 4; rg++) {
        int row = m0 + wave * 32 + i * 16 + cr + rg;
        int col = j * 16 + cc;
        float z = acc[i][j][rg] + ((col < 16) ? bfv[col] : blv[col - 16]);
        float s = 1.f / (1.f + __expf(-z));
        int bb = row >> 12, tt = row & 4095, hh = col & 15;
        float* dst = (col < 16) ? alpha : beta;
        dst[((size_t)(bb * 16 + hh)) * 4096 + tt] = s;
      }
}

// ------------------------ conv + rmsnorm + low-rank mix + k-tilde normalize
__global__ __launch_bounds__(256) void prep_kernel(
    const unsigned short* __restrict__ xqkv, const unsigned short* __restrict__ rqk,
    const float* __restrict__ cq, const float* __restrict__ ck,
    const float* __restrict__ cv, const float* __restrict__ gs,
    const float* __restrict__ qnw, const float* __restrict__ knw,
    unsigned short* __restrict__ qt, unsigned short* __restrict__ kt,
    unsigned short* __restrict__ vc) {
  int m = blockIdx.x;
  int b = m >> 12, t = m & 4095;
  int tid = threadIdx.x;
  int c4 = tid << 2;
  int h = c4 >> 6;
  int j4 = c4 & 63;

  float wq[4][4], wk[4][4], wv[4][4];
#pragma unroll
  for (int u = 0; u < 4; u++) {
    *(float4*)wq[u] = *(const float4*)(cq + (c4 + u) * 4);
    *(float4*)wk[u] = *(const float4*)(ck + (c4 + u) * 4);
    *(float4*)wv[u] = *(const float4*)(cv + (c4 + u) * 4);
  }
  float qv[4] = {0, 0, 0, 0}, kv[4] = {0, 0, 0, 0}, vv[4] = {0, 0, 0, 0};
#pragma unroll
  for (int j = 0; j < 4; j++) {
    int tt = t + j - 3;
    if (tt < 0) continue;
    const unsigned short* xr = xqkv + ((size_t)((b << 12) + tt)) * 3072;
    ushort4 uq = *(const ushort4*)(xr + c4);
    ushort4 uk = *(const ushort4*)(xr + 1024 + c4);
    ushort4 uv = *(const ushort4*)(xr + 2048 + c4);
    float xq[4] = {bf2f(uq.x), bf2f(uq.y), bf2f(uq.z), bf2f(uq.w)};
    float xk[4] = {bf2f(uk.x), bf2f(uk.y), bf2f(uk.z), bf2f(uk.w)};
    float xv[4] = {bf2f(uv.x), bf2f(uv.y), bf2f(uv.z), bf2f(uv.w)};
#pragma unroll
    for (int u = 0; u < 4; u++) {
      qv[u] = fmaf(wq[u][j], xq[u], qv[u]);
      kv[u] = fmaf(wk[u][j], xk[u], kv[u]);
      vv[u] = fmaf(wv[u][j], xv[u], vv[u]);
    }
  }
  float ssq = qv[0] * qv[0] + qv[1] * qv[1] + qv[2] * qv[2] + qv[3] * qv[3];
  ssq += __shfl_xor(ssq, 1); ssq += __shfl_xor(ssq, 2);
  ssq += __shfl_xor(ssq, 4); ssq += __shfl_xor(ssq, 8);
  float qsc = rsqrtf(ssq * (1.f / 64.f) + 1e-6f);
  float ssk = kv[0] * kv[0] + kv[1] * kv[1] + kv[2] * kv[2] + kv[3] * kv[3];
  ssk += __shfl_xor(ssk, 1); ssk += __shfl_xor(ssk, 2);
  ssk += __shfl_xor(ssk, 4); ssk += __shfl_xor(ssk, 8);
  float ksc = rsqrtf(ssk * (1.f / 64.f) + 1e-6f);

  float lam = fabsf(gs[h]);
  float rq[4] = {0, 0, 0, 0}, rk[4] = {0, 0, 0, 0};
  if (j4 < R_) {
    const unsigned short* rr = rqk + (size_t)m * 1536;
    ushort4 uq = *(const ushort4*)(rr + h * R_ + j4);
    ushort4 uk = *(const ushort4*)(rr + 768 + h * R_ + j4);
    rq[0] = bf2f(uq.x); rq[1] = bf2f(uq.y); rq[2] = bf2f(uq.z); rq[3] = bf2f(uq.w);
    rk[0] = bf2f(uk.x); rk[1] = bf2f(uk.y); rk[2] = bf2f(uk.z); rk[3] = bf2f(uk.w);
  }
  float qtv[4], ksum[4];
#pragma unroll
  for (int u = 0; u < 4; u++) {
    float qn = qv[u] * qsc * qnw[j4 + u];
    float kn = kv[u] * ksc * knw[j4 + u];
    qtv[u] = fmaf(lam, rq[u], qn);
    ksum[u] = fmaf(lam, rk[u], kn);
  }
  float ss2 = ksum[0] * ksum[0] + ksum[1] * ksum[1] + ksum[2] * ksum[2] +
              ksum[3] * ksum[3];
  ss2 += __shfl_xor(ss2, 1); ss2 += __shfl_xor(ss2, 2);
  ss2 += __shfl_xor(ss2, 4); ss2 += __shfl_xor(ss2, 8);
  float inv = 1.f / fmaxf(sqrtf(ss2), 1e-12f);

  size_t ob = ((size_t)((b * 16 + h) * 4096 + t)) * 64 + j4;
  ushort4 oq, ok, ov;
  oq.x = f2bf(qtv[0]); oq.y = f2bf(qtv[1]); oq.z = f2bf(qtv[2]); oq.w = f2bf(qtv[3]);
  ok.x = f2bf(ksum[0] * inv); ok.y = f2bf(ksum[1] * inv);
  ok.z = f2bf(ksum[2] * inv); ok.w = f2bf(ksum[3] * inv);
  ov.x = f2bf(vv[0]); ov.y = f2bf(vv[1]); ov.z = f2bf(vv[2]); ov.w = f2bf(vv[3]);
  *(ushort4*)(qt + ob) = oq;
  *(ushort4*)(kt + ob) = ok;
  *(ushort4*)(vc + ob) = ov;
}

// -------------------------------------------------------- gated delta scan
// 256 blocks (8 per bh, same-XCD), 2 waves/block, wave = 4 rows x 16 lanes.
// 8-step batched LDS->reg loads, then reg-only compute; padded LDS rows (65).
__global__ __launch_bounds__(128) void scan_kernel(
    const unsigned short* __restrict__ qt, const unsigned short* __restrict__ kt,
    const unsigned short* __restrict__ vc, const float* __restrict__ al,
    const float* __restrict__ be, float* __restrict__ attn) {
  __shared__ alignas(16) float sk[2][CHUNK][65];
  __shared__ alignas(16) float sq[2][CHUNK][65];
  __shared__ alignas(16) float sv[2][CHUNK][8];

  int i = blockIdx.x;
  int bh = i & 31;   // i%8 == bh%8 -> all 8 blocks of a bh on one XCD
  int grp = i >> 5;  // 0..7 -> rows grp*8..+7
  int b = bh >> 4, h = bh & 15;
  int tid = threadIdx.x;
  int w = tid >> 6, l = tid & 63;
  int rw = l >> 4;        // row in wave (0..3)
  int li = l & 15;        // lane in DPP row
  int vr = w * 4 + rw;    // row in block (0..7)
  int r = grp * 8 + vr;   // global row
  int c = li * 4;

  const unsigned short* kb = kt + (size_t)bh * S_ * 64;
  const unsigned short* qb = qt + (size_t)bh * S_ * 64;
  const unsigned short* vb = vc + (size_t)bh * S_ * 64 + grp * 8;
  const float* ap = al + (size_t)bh * S_;
  const float* bp = be + (size_t)bh * S_;
  float* op = attn + (size_t)(b * S_) * 1024 + h * 64 + r;

  float mem[4] = {0.f, 0.f, 0.f, 0.f};

  // prefetch chunk 0 into regs: 16 bf16 of k and q per thread, 2 v, 1 gate.
  short8 rk0 = *(const short8*)(kb + tid * 16);
  short8 rk1 = *(const short8*)(kb + tid * 16 + 8);
  short8 rq0 = *(const short8*)(qb + tid * 16);
  short8 rq1 = *(const short8*)(qb + tid * 16 + 8);
  ushort2 rv = *(const ushort2*)(vb + (size_t)(tid >> 2) * 64 + (tid & 3) * 2);
  float rab = (l < 32) ? ap[l] : bp[l - 32];  // per-wave copy

  const int nc = S_ / CHUNK;
  for (int cch = 0; cch < nc; ++cch) {
    int p = cch & 1;
    unsigned rab_c = __float_as_uint(rab);  // preserve current-chunk gates
    __syncthreads();
    {  // regs -> LDS (bf16 -> f32). thread covers sk[p][tid>>2][(tid&3)*16..+16)
      int t = tid >> 2, ch = (tid & 3) * 16;
      float* dk = &sk[p][t][ch];
      float* dq = &sq[p][t][ch];
      f32x4 f;
#pragma unroll
      for (int j = 0; j < 4; j++) f[j] = bf2f((unsigned short)rk0[j]);
      *(f32x4*)dk = f;
#pragma unroll
      for (int j = 0; j < 4; j++) f[j] = bf2f((unsigned short)rk0[4 + j]);
      *(f32x4*)(dk + 4) = f;
#pragma unroll
      for (int j = 0; j < 4; j++) f[j] = bf2f((unsigned short)rk1[j]);
      *(f32x4*)(dk + 8) = f;
#pragma unroll
      for (int j = 0; j < 4; j++) f[j] = bf2f((unsigned short)rk1[4 + j]);
      *(f32x4*)(dk + 12) = f;
#pragma unroll
      for (int j = 0; j < 4; j++) f[j] = bf2f((unsigned short)rq0[j]);
      *(f32x4*)dq = f;
#pragma unroll
      for (int j = 0; j < 4; j++) f[j] = bf2f((unsigned short)rq0[4 + j]);
      *(f32x4*)(dq + 4) = f;
#pragma unroll
      for (int j = 0; j < 4; j++) f[j] = bf2f((unsigned short)rq1[j]);
      *(f32x4*)(dq + 8) = f;
#pragma unroll
      for (int j = 0; j < 4; j++) f[j] = bf2f((unsigned short)rq1[4 + j]);
      *(f32x4*)(dq + 12) = f;
      sv[p][tid >> 2][(tid & 3) * 2] = bf2f(rv.x);
      sv[p][tid >> 2][(tid & 3) * 2 + 1] = bf2f(rv.y);
    }
    if (cch + 1 < nc) {  // issue next-chunk loads; in flight during compute
      size_t cb = (size_t)(cch + 1) * (CHUNK * 64);
      rk0 = *(const short8*)(kb + cb + tid * 16);
      rk1 = *(const short8*)(kb + cb + tid * 16 + 8);
      rq0 = *(const short8*)(qb + cb + tid * 16);
      rq1 = *(const short8*)(qb + cb + tid * 16 + 8);
      rv = *(const ushort2*)(vb + cb + (size_t)(tid >> 2) * 64 + (tid & 3) * 2);
      int ct = (cch + 1) * CHUNK;
      rab = (l < 32) ? ap[ct + l] : bp[ct + l - 32];
    }
    __syncthreads();
    int tg0 = cch * CHUNK;
#pragma unroll
    for (int tb = 0; tb < CHUNK; tb += 8) {
      // batched LDS -> reg for 8 steps (amortize LDS latency)
      f32x4 kr[8], qr[8];
      float v8[8];
#pragma unroll
      for (int j = 0; j < 8; j++) {
        kr[j] = *(const f32x4*)&sk[p][tb + j][c];
        qr[j] = *(const f32x4*)&sq[p][tb + j][c];
        v8[j] = sv[p][tb + j][vr];
      }
#pragma unroll
      for (int j = 0; j < 8; j++) {
        f32x4 kf = kr[j], qf = qr[j];
        float a = __uint_as_float(__builtin_amdgcn_readlane(rab_c, tb + j));
        float bg =
            __uint_as_float(__builtin_amdgcn_readlane(rab_c, tb + j + 32));

        float mk_p = fmaf(mem[1], kf[1], mem[0] * kf[0]) +
                     fmaf(mem[3], kf[3], mem[2] * kf[2]);
        float mq_p = fmaf(mem[1], qf[1], mem[0] * qf[0]) +
                     fmaf(mem[3], qf[3], mem[2] * qf[2]);
        float kq_p = fmaf(kf[1], qf[1], kf[0] * qf[0]) +
                     fmaf(kf[3], qf[3], kf[2] * qf[2]);
        float mk = redrow16(mk_p);
        float mq = redrow16(mq_p);
        float kq = redrow16(kq_p);

        float bd = bg * (v8[j] - mk);
        float oo = fmaf(bd, kq, a * mq);
#pragma unroll
        for (int u = 0; u < 4; u++) mem[u] = fmaf(bd, kf[u], a * mem[u]);
        if (li == 0) op[(size_t)(tg0 + tb + j) * 1024] = oo;
      }
    }
  }
}

// ------------------------------------------------ output rmsnorm -> bf16 rows
__global__ __launch_bounds__(256) void rmsnorm_out_kernel(
    const float* __restrict__ attn, const float* __restrict__ onw,
    unsigned short* __restrict__ normed) {
  int m = blockIdx.x, tid = threadIdx.x;
  const float* row = attn + (size_t)m * 1024;
  float xv[4];
  *(float4*)xv = *(const float4*)(row + tid * 4);
  float ss = xv[0] * xv[0] + xv[1] * xv[1] + xv[2] * xv[2] + xv[3] * xv[3];
#pragma unroll
  for (int o = 1; o < 64; o <<= 1) ss += __shfl_xor(ss, o);
  __shared__ float wss[4];
  if ((tid & 63) == 0) wss[tid >> 6] = ss;
  __syncthreads();
  float tot = wss[0] + wss[1] + wss[2] + wss[3];
  float sc = rsqrtf(tot * (1.f / 1024.f) + 1e-6f);
  float wv[4];
  *(float4*)wv = *(const float4*)(onw + tid * 4);
  ushort4 o4;
  o4.x = f2bf(xv[0] * sc * wv[0]);
  o4.y = f2bf(xv[1] * sc * wv[1]);
  o4.z = f2bf(xv[2] * sc * wv[2]);
  o4.w = f2bf(xv[3] * sc * wv[3]);
  *(ushort4*)(normed + (size_t)m * 1024 + tid * 4) = o4;
}

// ---------------------------------------------------------------------------
extern "C" void kernel_launch(void* const* d_in, const int* in_sizes, int n_in,
                              void* d_out, int out_size, void* d_ws,
                              size_t ws_size, hipStream_t stream) {
  const float* x = (const float*)d_in[0];
  const float* Wq = (const float*)d_in[1];
  const float* Wk = (const float*)d_in[2];
  const float* Wv = (const float*)d_in[3];
  const float* Wo = (const float*)d_in[4];
  const float* conv_q = (const float*)d_in[5];
  const float* conv_k = (const float*)d_in[6];
  const float* conv_v = (const float*)d_in[7];
  const float* Wf = (const float*)d_in[8];
  const float* bfv = (const float*)d_in[9];
  const float* Wl = (const float*)d_in[10];
  const float* blv = (const float*)d_in[11];
  const float* gs = (const float*)d_in[14];
  const float* qn_w = (const float*)d_in[15];
  const float* kn_w = (const float*)d_in[16];
  const float* on_w = (const float*)d_in[17];

  char* ws = (char*)d_ws;
  size_t used = 0;
  auto alloc = [&](size_t bytes) -> void* {
    void* p = (void*)(ws + used);
    used += (bytes + 255) & ~(size_t)255;
    return p;
  };
  unsigned short* xb = (unsigned short*)alloc((size_t)M_ * D_ * 2);
  unsigned short* wqkv_t = (unsigned short*)alloc((size_t)3072 * 1024 * 2);
  unsigned short* wr_t = (unsigned short*)alloc((size_t)1536 * 1024 * 2);
  unsigned short* wo_t = (unsigned short*)alloc((size_t)1024 * 1024 * 2);
  unsigned short* wfl = (unsigned short*)alloc((size_t)32 * 1024 * 2);
  unsigned short* xqkv = (unsigned short*)alloc((size_t)M_ * 3072 * 2);
  unsigned short* rqk = (unsigned short*)alloc((size_t)M_ * 1536 * 2);
  unsigned short* qt = (unsigned short*)alloc((size_t)M_ * 1024 * 2);
  unsigned short* kt = (unsigned short*)alloc((size_t)M_ * 1024 * 2);
  unsigned short* vc = (unsigned short*)alloc((size_t)M_ * 1024 * 2);
  float* alpha = (float*)alloc((size_t)B_ * H_ * S_ * 4);
  float* beta = (float*)alloc((size_t)B_ * H_ * S_ * 4);
  float* attn = (float*)xqkv;    // alias (xqkv dead after prep)
  unsigned short* normed = rqk;  // alias (rqk dead after prep)

  if (used > ws_size) return;

  cast_bf16_kernel<<<2048, 256, 0, stream>>>(x, xb, M_ * D_ / 4);

  dim3 tb(32, 8);
  transpose_w_kernel<<<dim3(32, 32), tb, 0, stream>>>(Wq, wqkv_t, 1024, 1024);
  transpose_w_kernel<<<dim3(32, 32), tb, 0, stream>>>(
      Wk, wqkv_t + (size_t)1024 * 1024, 1024, 1024);
  transpose_w_kernel<<<dim3(32, 32), tb, 0, stream>>>(
      Wv, wqkv_t + (size_t)2048 * 1024, 1024, 1024);
  transpose_w_kernel<<<dim3(24, 32), tb, 0, stream>>>(
      (const float*)d_in[12], wr_t, 1024, 768);
  transpose_w_kernel<<<dim3(24, 32), tb, 0, stream>>>(
      (const float*)d_in[13], wr_t + (size_t)768 * 1024, 1024, 768);
  transpose_w_kernel<<<dim3(32, 32), tb, 0, stream>>>(Wo, wo_t, 1024, 1024);
  pack_wfl_kernel<<<128, 256, 0, stream>>>(Wf, Wl, wfl);

  gemm_bt_kernel<true><<<64 * 24, 256, 0, stream>>>(xb, wqkv_t, xqkv, M_, 3072, 1024);
  gemm_bt_kernel<true><<<64 * 12, 256, 0, stream>>>(xb, wr_t, rqk, M_, 1536, 1024);

  fl_gemm_kernel<<<64, 256, 0, stream>>>(xb, wfl, bfv, blv, alpha, beta);

  prep_kernel<<<M_, 256, 0, stream>>>(xqkv, rqk, conv_q, conv_k, conv_v, gs,
                                      qn_w, kn_w, qt, kt, vc);

  scan_kernel<<<256, 128, 0, stream>>>(qt, kt, vc, alpha, beta, attn);

  rmsnorm_out_kernel<<<M_, 256, 0, stream>>>(attn, on_w, normed);

  gemm_bt_kernel<false><<<64 * 8, 256, 0, stream>>>(normed, wo_t, (float*)d_out,
                                                    M_, 1024, 1024);
}